// Round 2
// baseline (2271.018 us; speedup 1.0000x reference)
//
#include <hip/hip_runtime.h>
#include <hip/hip_bf16.h>
#include <stdint.h>

#define VV 32000
#define HH 128
#define BB 8
#define SS 512
#define NNODE 50000
#define NEDGE 600000

typedef __attribute__((ext_vector_type(8))) short s16x8;
typedef __attribute__((ext_vector_type(4))) float f32x4;

// ---------------- embedding gather + encoder input-gate GEMM ----------------
// xg[b,t,g] = emb[json[b,t]] . W_ih[g,:] + b[g]      (4096 x 512)
__global__ __launch_bounds__(256) void xg_enc_kernel(
    const int* __restrict__ jin, const float* __restrict__ emb,
    const float* __restrict__ Wih, const float* __restrict__ bvec,
    float* __restrict__ xg)
{
  __shared__ __align__(16) float arow[8][128];
  const int tid = threadIdx.x, blk = blockIdx.x;
  {
    int r = tid >> 5, c = (tid & 31) << 2;
    int tok = jin[blk*8 + r];
    *(float4*)&arow[r][c] = *(const float4*)&emb[(size_t)tok*HH + c];
  }
  __syncthreads();
  const int g0 = tid * 2;
  const float* w0 = Wih + (size_t)g0*HH;
  const float* w1 = w0 + HH;
  float acc0[8], acc1[8];
  #pragma unroll
  for (int r=0;r<8;r++){ acc0[r]=0.f; acc1[r]=0.f; }
  for (int k=0;k<HH;k+=4) {
    float4 wa = *(const float4*)&w0[k];
    float4 wb = *(const float4*)&w1[k];
    #pragma unroll
    for (int r=0;r<8;r++) {
      float4 av = *(const float4*)&arow[r][k];
      acc0[r] += av.x*wa.x + av.y*wa.y + av.z*wa.z + av.w*wa.w;
      acc1[r] += av.x*wb.x + av.y*wb.y + av.z*wb.z + av.w*wb.w;
    }
  }
  float bb0 = bvec[g0], bb1 = bvec[g0+1];
  #pragma unroll
  for (int r=0;r<8;r++) {
    size_t row = (size_t)blk*8 + r;
    xg[row*512 + g0]     = acc0[r] + bb0;
    xg[row*512 + g0 + 1] = acc1[r] + bb1;
  }
}

// ---------------- LSTM scan: 1 workgroup (256 thr) per batch element ----------------
// Thread tid owns gate rows r0=tid and r1=tid+256:
//   tid in [0,128):  r0 -> gate i (j=tid),     r1 -> gate g (j=tid)
//   tid in [128,256): r0 -> gate f (j=tid-128), r1 -> gate o (j=tid-128)
// W rows pinned in VGPRs (256 regs) via asm; h broadcast from LDS.
// MODE 0 (encoder): xg is [B][S][512]; outputs hmean[b][128]
// MODE 1 (decoder): xg is [B][512] (time-constant); outputs split-bf16 h rows
template<int MODE>
__global__ __launch_bounds__(256, 1) void lstm_scan_kernel(
    const float* __restrict__ xg, const float* __restrict__ Whh,
    float* __restrict__ hmean,
    __hip_bfloat16* __restrict__ ahi, __hip_bfloat16* __restrict__ alo)
{
  __shared__ __align__(16) float h_s[128];
  __shared__ __align__(8) float2 fo_s[128];
  const int b = blockIdx.x, tid = threadIdx.x;
  const int r1base = tid + 256;

  float w0[128], w1[128];
  #pragma unroll
  for (int k=0;k<128;k+=4) {
    *(float4*)&w0[k] = *(const float4*)&Whh[(size_t)tid*HH + k];
    *(float4*)&w1[k] = *(const float4*)&Whh[(size_t)r1base*HH + k];
  }
  // Pin weights in VGPRs: asm makes values opaque -> no rematerialization.
  #pragma unroll
  for (int k=0;k<128;k++) {
    asm volatile("" : "+v"(w0[k]));
    asm volatile("" : "+v"(w1[k]));
  }

  float x0, x1;
  if (MODE==1) {
    x0 = xg[b*512 + tid];
    x1 = xg[b*512 + r1base];
  }
  const float* xgrow = (MODE==0) ? (xg + (size_t)b*SS*512) : (const float*)0;
  if (MODE==0) {
    x0 = xgrow[tid];
    x1 = xgrow[r1base];
  }
  if (tid < 128) h_s[tid] = 0.f;
  float cstate = 0.f, hsum = 0.f;
  __syncthreads();

  for (int t=0;t<SS;t++) {
    float nx0, nx1;
    if (MODE==0) {                       // prefetch next step's x
      int tn = (t < SS-1) ? (t+1) : t;
      nx0 = xgrow[(size_t)tn*512 + tid];
      nx1 = xgrow[(size_t)tn*512 + r1base];
    }
    float a00=0.f,a01=0.f,a02=0.f,a03=0.f;
    float a10=0.f,a11=0.f,a12=0.f,a13=0.f;
    #pragma unroll
    for (int k=0;k<32;k++) {
      float4 hv = *(const float4*)&h_s[k*4];   // wave-uniform -> LDS broadcast
      a00 += w0[k*4+0]*hv.x; a01 += w0[k*4+1]*hv.y;
      a02 += w0[k*4+2]*hv.z; a03 += w0[k*4+3]*hv.w;
      a10 += w1[k*4+0]*hv.x; a11 += w1[k*4+1]*hv.y;
      a12 += w1[k*4+2]*hv.z; a13 += w1[k*4+3]*hv.w;
    }
    float s0 = (a00+a01)+(a02+a03) + x0;
    float s1 = (a10+a11)+(a12+a13) + x1;
    if (tid < 128) {
      float iv = 1.0f/(1.0f+expf(-s0));
      float gv = tanhf(s1);
      __syncthreads();                       // fo_s ready
      float2 fo = fo_s[tid];
      cstate = fo.x*cstate + iv*gv;
      float hh = fo.y*tanhf(cstate);
      h_s[tid] = hh;
      if (MODE==0) {
        hsum += hh;
      } else {
        size_t row = (size_t)b*SS + t;
        __hip_bfloat16 hi = __float2bfloat16(hh);
        float rem = hh - __bfloat162float(hi);
        ahi[row*HH + tid] = hi;
        alo[row*HH + tid] = __float2bfloat16(rem);
      }
    } else {
      float fv = 1.0f/(1.0f+expf(-s0));
      float ov = 1.0f/(1.0f+expf(-s1));
      fo_s[tid-128] = make_float2(fv, ov);
      __syncthreads();                       // matches barrier above
    }
    if (MODE==0) { x0 = nx0; x1 = nx1; }
    __syncthreads();                         // h_s ready for next step
  }
  if (MODE==0 && tid < 128) hmean[b*HH + tid] = hsum * (1.0f/512.0f);
}

// ---------------- graph branch (collapsed to scalar edge passes) ----------------
__global__ __launch_bounds__(256) void edge_deg_kernel(const int* __restrict__ dst, float* __restrict__ deg) {
  int i = blockIdx.x*256 + threadIdx.x;
  if (i < NEDGE) atomicAdd(&deg[dst[i]], 1.0f);
}
__global__ __launch_bounds__(256) void node_dinv_kernel(const float* __restrict__ deg, float* __restrict__ dinv) {
  int n = blockIdx.x*256 + threadIdx.x;
  if (n < NNODE) dinv[n] = 1.0f / sqrtf(deg[n] + 1.0f);
}
__global__ __launch_bounds__(256) void edge_s1_kernel(const int* __restrict__ src, const int* __restrict__ dst,
    const float* __restrict__ dinv, float* __restrict__ s1) {
  int i = blockIdx.x*256 + threadIdx.x;
  if (i < NEDGE) atomicAdd(&s1[src[i]], dinv[dst[i]]);
}
__global__ __launch_bounds__(256) void node_c_kernel(const float* __restrict__ dinv, const float* __restrict__ s1,
    float* __restrict__ cc, float* __restrict__ csum) {
  __shared__ float red[256];
  int tid = threadIdx.x;
  int n = blockIdx.x*256 + tid;
  float v = 0.f;
  if (n < NNODE) { float d = dinv[n]; v = d*s1[n] + d*d; cc[n] = v; }
  red[tid] = v; __syncthreads();
  for (int sfl=128; sfl>0; sfl>>=1) { if (tid < sfl) red[tid] += red[tid+sfl]; __syncthreads(); }
  if (tid==0) atomicAdd(csum, red[0]);
}
__global__ __launch_bounds__(256) void edge_s2_kernel(const int* __restrict__ src, const int* __restrict__ dst,
    const float* __restrict__ dinv, const float* __restrict__ cc, float* __restrict__ s2) {
  int i = blockIdx.x*256 + threadIdx.x;
  if (i < NEDGE) { int d = dst[i]; atomicAdd(&s2[src[i]], cc[d]*dinv[d]); }
}
__global__ __launch_bounds__(256) void node_e_kernel(const float* __restrict__ dinv, const float* __restrict__ s2,
    const float* __restrict__ cc, float* __restrict__ ee) {
  int n = blockIdx.x*256 + threadIdx.x;
  if (n < NNODE) { float d = dinv[n]; ee[n] = d*s2[n] + cc[n]*d*d; }
}
// gvec[j] = sum_n ee[n] * emb[node_ids[n]][j]
__global__ __launch_bounds__(256) void gvec_kernel(const int* __restrict__ nids, const float* __restrict__ emb,
    const float* __restrict__ ee, float* __restrict__ gvec) {
  __shared__ float red[256];
  int tid = threadIdx.x;
  int j = tid & 127, sub = tid >> 7;
  float acc = 0.f;
  for (int n = blockIdx.x*2 + sub; n < NNODE; n += gridDim.x*2) {
    acc += ee[n] * emb[(size_t)nids[n]*HH + j];
  }
  red[tid] = acc; __syncthreads();
  if (tid < 128) atomicAdd(&gvec[j], red[tid] + red[tid+128]);
}
// m = ((gvec @ W1^T + csum*b1) @ W2^T)/N + b2
__global__ void graph_final_kernel(const float* __restrict__ gvec, const float* __restrict__ csum,
    const float* __restrict__ W1, const float* __restrict__ b1,
    const float* __restrict__ W2, const float* __restrict__ b2, float* __restrict__ mvec) {
  __shared__ float gs[128], v1[128];
  int j = threadIdx.x;
  gs[j] = gvec[j];
  __syncthreads();
  float a = 0.f;
  for (int k=0;k<128;k++) a += gs[k]*W1[j*128+k];
  v1[j] = a + csum[0]*b1[j];
  __syncthreads();
  float a2 = 0.f;
  for (int k=0;k<128;k++) a2 += v1[k]*W2[j*128+k];
  mvec[j] = a2 * (1.0f/(float)NNODE) + b2[j];
}

// ---------------- fusion: fused = [hmean, m] @ Wf^T + bf ; xg_dec = fused @ Wihd^T + bd ----------------
__global__ __launch_bounds__(512) void fusion_kernel(const float* __restrict__ hmean, const float* __restrict__ mvec,
    const float* __restrict__ Wf, const float* __restrict__ bfv,
    const float* __restrict__ Wihd, const float* __restrict__ bd, float* __restrict__ xgdec)
{
  __shared__ float comb[256];
  __shared__ float fus[128];
  int b = blockIdx.x, tid = threadIdx.x;
  if (tid < 128) comb[tid] = hmean[b*128 + tid];
  else if (tid < 256) comb[tid] = mvec[tid - 128];
  __syncthreads();
  if (tid < 128) {
    float a = 0.f;
    for (int k=0;k<256;k++) a += comb[k]*Wf[tid*256+k];
    fus[tid] = a + bfv[tid];
  }
  __syncthreads();
  float a = 0.f;
  for (int k=0;k<128;k++) a += fus[k]*Wihd[tid*128+k];
  xgdec[b*512 + tid] = a + bd[tid];
}

// ---------------- split fp32 -> (bf16 hi, bf16 lo) ----------------
__global__ __launch_bounds__(256) void split_bf16_kernel(const float* __restrict__ x,
    __hip_bfloat16* __restrict__ hi, __hip_bfloat16* __restrict__ lo, int n4) {
  int i = blockIdx.x*256 + threadIdx.x;
  if (i >= n4) return;
  float4 v = *(const float4*)&x[i*4];
  float vv[4] = {v.x, v.y, v.z, v.w};
  #pragma unroll
  for (int k=0;k<4;k++) {
    __hip_bfloat16 h = __float2bfloat16(vv[k]);
    hi[i*4+k] = h;
    lo[i*4+k] = __float2bfloat16(vv[k] - __bfloat162float(h));
  }
}

// ---------------- output GEMM: [4096,128] @ Wo^T -> [4096,32000], split-bf16 MFMA ----------------
// 64x64 tile, 4 waves (2x2), 16x16x32 bf16 MFMA, 3 products (hh, hl, lh).
__global__ __launch_bounds__(256) void out_gemm_kernel(
    const __hip_bfloat16* __restrict__ Ahi, const __hip_bfloat16* __restrict__ Alo,
    const __hip_bfloat16* __restrict__ Bhi, const __hip_bfloat16* __restrict__ Blo,
    const float* __restrict__ bo, float* __restrict__ out)
{
  __shared__ __align__(16) short smem[4*64*128];   // 4 planes x 16KB = 64KB
  const int tid = threadIdx.x;
  const int bid = blockIdx.x;
  const int mblk = bid & 63;        // 64 M-tiles (m fast: consecutive blocks share B tile)
  const int nblk = bid >> 6;        // 500 N-tiles
  const short* srcs[4] = {
    (const short*)Ahi + (size_t)mblk*64*HH,
    (const short*)Alo + (size_t)mblk*64*HH,
    (const short*)Bhi + (size_t)nblk*64*HH,
    (const short*)Blo + (size_t)nblk*64*HH };
  const int wuni  = (tid >> 6) * 1024;   // wave-uniform byte offset
  const int lbyte = (tid & 63) * 16;
  #pragma unroll
  for (int p=0;p<4;p++) {
    #pragma unroll
    for (int it=0; it<4; it++) {
      int off  = it*4096 + wuni + lbyte;         // linear byte offset in plane
      int row  = off >> 8;                        // 256B per row
      int soff = off ^ ((row & 15) << 4);         // inverse swizzle on the SOURCE (rule #21)
      __builtin_amdgcn_global_load_lds(
        (const __attribute__((address_space(1))) void*)((const char*)srcs[p] + soff),
        (__attribute__((address_space(3))) void*)((char*)smem + p*16384 + it*4096 + wuni),
        16, 0, 0);
    }
  }
  __syncthreads();

  const int lane = tid & 63;
  const int wid  = tid >> 6;
  const int wm = wid >> 1, wn = wid & 1;
  const int l15 = lane & 15, l4 = lane >> 4;

  f32x4 acc[2][2] = {};
  #pragma unroll
  for (int s=0;s<4;s++) {
    s16x8 ah[2], al[2], bh[2], bl[2];
    #pragma unroll
    for (int q=0;q<2;q++) {
      int ra   = wm*32 + q*16 + l15;
      int offa = (ra*256 + s*64 + l4*16) ^ ((ra & 15) << 4);  // swizzled read
      ah[q] = *(const s16x8*)((const char*)smem + offa);
      al[q] = *(const s16x8*)((const char*)smem + 16384 + offa);
      int rb   = wn*32 + q*16 + l15;
      int offb = (rb*256 + s*64 + l4*16) ^ ((rb & 15) << 4);
      bh[q] = *(const s16x8*)((const char*)smem + 32768 + offb);
      bl[q] = *(const s16x8*)((const char*)smem + 49152 + offb);
    }
    #pragma unroll
    for (int mi=0;mi<2;mi++) {
      #pragma unroll
      for (int ni=0;ni<2;ni++) {
        acc[mi][ni] = __builtin_amdgcn_mfma_f32_16x16x32_bf16(ah[mi], bh[ni], acc[mi][ni], 0,0,0);
        acc[mi][ni] = __builtin_amdgcn_mfma_f32_16x16x32_bf16(ah[mi], bl[ni], acc[mi][ni], 0,0,0);
        acc[mi][ni] = __builtin_amdgcn_mfma_f32_16x16x32_bf16(al[mi], bh[ni], acc[mi][ni], 0,0,0);
      }
    }
  }
  const int m0 = mblk*64 + wm*32;
  const int n0 = nblk*64 + wn*32;
  #pragma unroll
  for (int ni=0;ni<2;ni++) {
    int col = n0 + ni*16 + l15;
    float bov = bo[col];
    #pragma unroll
    for (int mi=0;mi<2;mi++) {
      #pragma unroll
      for (int r=0;r<4;r++) {
        int row = m0 + mi*16 + l4*4 + r;     // C/D: col=lane&15, row=(lane>>4)*4+reg
        out[(size_t)row*VV + col] = acc[mi][ni][r] + bov;
      }
    }
  }
}

// ---------------- launch ----------------
extern "C" void kernel_launch(void* const* d_in, const int* in_sizes, int n_in,
                              void* d_out, int out_size, void* d_ws, size_t ws_size,
                              hipStream_t stream)
{
  (void)in_sizes; (void)n_in; (void)out_size; (void)ws_size;
  const int*   jin   = (const int*)d_in[0];
  const int*   nids  = (const int*)d_in[1];
  const int*   esrc  = (const int*)d_in[2];
  const int*   edst  = esrc + NEDGE;
  const float* emb   = (const float*)d_in[3];
  const float* WihE  = (const float*)d_in[4];
  const float* WhhE  = (const float*)d_in[5];
  const float* bE    = (const float*)d_in[6];
  const float* W1    = (const float*)d_in[7];
  const float* b1    = (const float*)d_in[8];
  const float* W2    = (const float*)d_in[9];
  const float* b2    = (const float*)d_in[10];
  const float* Wf    = (const float*)d_in[11];
  const float* bfv   = (const float*)d_in[12];
  const float* WihD  = (const float*)d_in[13];
  const float* WhhD  = (const float*)d_in[14];
  const float* bD    = (const float*)d_in[15];
  const float* Wo    = (const float*)d_in[16];
  const float* bo    = (const float*)d_in[17];
  float* out = (float*)d_out;

  char* ws = (char*)d_ws;
  size_t off = 0;
  auto alloc = [&](size_t bytes) { size_t o = off; off = (off + bytes + 255) & ~(size_t)255; return o; };

  float* deg  = (float*)(ws + alloc(NNODE*4));
  float* s1   = (float*)(ws + alloc(NNODE*4));
  float* s2   = (float*)(ws + alloc(NNODE*4));
  float* gvec = (float*)(ws + alloc(128*4));
  float* csum = (float*)(ws + alloc(4));
  size_t zero_bytes = off;                       // [deg,s1,s2,gvec,csum] zeroed each call
  float* dinv = (float*)(ws + alloc(NNODE*4));
  float* cc   = (float*)(ws + alloc(NNODE*4));
  float* ee   = (float*)(ws + alloc(NNODE*4));
  float* mvec = (float*)(ws + alloc(128*4));
  float* hmean= (float*)(ws + alloc(BB*HH*4));
  float* xgdec= (float*)(ws + alloc(BB*512*4));
  float* xgenc= (float*)(ws + alloc((size_t)BB*SS*512*4));
  __hip_bfloat16* Ahi = (__hip_bfloat16*)(ws + alloc((size_t)BB*SS*HH*2));
  __hip_bfloat16* Alo = (__hip_bfloat16*)(ws + alloc((size_t)BB*SS*HH*2));
  __hip_bfloat16* Bhi = (__hip_bfloat16*)(ws + alloc((size_t)VV*HH*2));
  __hip_bfloat16* Blo = (__hip_bfloat16*)(ws + alloc((size_t)VV*HH*2));

  hipMemsetAsync(ws, 0, zero_bytes, stream);

  // sequence branch
  xg_enc_kernel<<<dim3((BB*SS)/8), dim3(256), 0, stream>>>(jin, emb, WihE, bE, xgenc);
  lstm_scan_kernel<0><<<dim3(BB), dim3(256), 0, stream>>>(xgenc, WhhE, hmean, nullptr, nullptr);

  // graph branch (collapsed)
  edge_deg_kernel<<<dim3((NEDGE+255)/256), dim3(256), 0, stream>>>(edst, deg);
  node_dinv_kernel<<<dim3((NNODE+255)/256), dim3(256), 0, stream>>>(deg, dinv);
  edge_s1_kernel<<<dim3((NEDGE+255)/256), dim3(256), 0, stream>>>(esrc, edst, dinv, s1);
  node_c_kernel<<<dim3((NNODE+255)/256), dim3(256), 0, stream>>>(dinv, s1, cc, csum);
  edge_s2_kernel<<<dim3((NEDGE+255)/256), dim3(256), 0, stream>>>(esrc, edst, dinv, cc, s2);
  node_e_kernel<<<dim3((NNODE+255)/256), dim3(256), 0, stream>>>(dinv, s2, cc, ee);
  gvec_kernel<<<dim3(256), dim3(256), 0, stream>>>(nids, emb, ee, gvec);
  graph_final_kernel<<<dim3(1), dim3(128), 0, stream>>>(gvec, csum, W1, b1, W2, b2, mvec);

  // fusion + decoder
  fusion_kernel<<<dim3(BB), dim3(512), 0, stream>>>(hmean, mvec, Wf, bfv, WihD, bD, xgdec);
  lstm_scan_kernel<1><<<dim3(BB), dim3(256), 0, stream>>>(xgdec, WhhD, nullptr, Ahi, Alo);

  // output projection
  split_bf16_kernel<<<dim3((VV*HH/4+255)/256), dim3(256), 0, stream>>>(Wo, Bhi, Blo, VV*HH/4);
  out_gemm_kernel<<<dim3(64*(VV/64)), dim3(256), 0, stream>>>(Ahi, Alo, Bhi, Blo, bo, out);
}

// Round 3
// 1727.006 us; speedup vs baseline: 1.3150x; 1.3150x over previous
//
#include <hip/hip_runtime.h>
#include <hip/hip_bf16.h>
#include <stdint.h>

#define VV 32000
#define HH 128
#define BB 8
#define SS 512
#define NNODE 50000
#define NEDGE 600000

typedef __attribute__((ext_vector_type(8))) short s16x8;
typedef __attribute__((ext_vector_type(4))) float f32x4;

__device__ __forceinline__ float bcast_lane(float v, int l) {
  return __int_as_float(__builtin_amdgcn_readlane(__float_as_int(v), l));
}

// ---------------- embedding gather + encoder input-gate GEMM ----------------
__global__ __launch_bounds__(256) void xg_enc_kernel(
    const int* __restrict__ jin, const float* __restrict__ emb,
    const float* __restrict__ Wih, const float* __restrict__ bvec,
    float* __restrict__ xg)
{
  __shared__ __align__(16) float arow[8][128];
  const int tid = threadIdx.x, blk = blockIdx.x;
  {
    int r = tid >> 5, c = (tid & 31) << 2;
    int tok = jin[blk*8 + r];
    *(float4*)&arow[r][c] = *(const float4*)&emb[(size_t)tok*HH + c];
  }
  __syncthreads();
  const int g0 = tid * 2;
  const float* w0 = Wih + (size_t)g0*HH;
  const float* w1 = w0 + HH;
  float acc0[8], acc1[8];
  #pragma unroll
  for (int r=0;r<8;r++){ acc0[r]=0.f; acc1[r]=0.f; }
  for (int k=0;k<HH;k+=4) {
    float4 wa = *(const float4*)&w0[k];
    float4 wb = *(const float4*)&w1[k];
    #pragma unroll
    for (int r=0;r<8;r++) {
      float4 av = *(const float4*)&arow[r][k];
      acc0[r] += av.x*wa.x + av.y*wa.y + av.z*wa.z + av.w*wa.w;
      acc1[r] += av.x*wb.x + av.y*wb.y + av.z*wb.z + av.w*wb.w;
    }
  }
  float bb0 = bvec[g0], bb1 = bvec[g0+1];
  #pragma unroll
  for (int r=0;r<8;r++) {
    size_t row = (size_t)blk*8 + r;
    xg[row*512 + g0]     = acc0[r] + bb0;
    xg[row*512 + g0 + 1] = acc1[r] + bb1;
  }
}

// ---------------- LSTM scan: 1 workgroup (512 thr) per batch element ----------------
// Thread t owns gate row g = t (i:0-127, f:128-255, g:256-383, o:384-511).
// 128 weight floats/thread pinned in VGPRs (fits under the 256 ArchVGPR cap).
// h broadcast via v_readlane (SGPR) instead of uniform LDS reads.
template<int MODE>
__global__ __launch_bounds__(512, 2) void lstm_scan_kernel(
    const float* __restrict__ xg, const float* __restrict__ Whh,
    float* __restrict__ hmean,
    __hip_bfloat16* __restrict__ ahi, __hip_bfloat16* __restrict__ alo)
{
  __shared__ float h_s[128];
  __shared__ float act_s[512];
  const int b = blockIdx.x, tid = threadIdx.x;
  const int lane = tid & 63;

  float w[128];
  #pragma unroll
  for (int k=0;k<128;k+=4)
    *(float4*)&w[k] = *(const float4*)&Whh[(size_t)tid*HH + k];
  #pragma unroll
  for (int k=0;k<128;k++) asm volatile("" : "+v"(w[k]));   // pin in VGPRs

  float xv;
  const float* xgrow = nullptr;
  if (MODE==1) {
    xv = xg[b*512 + tid];
  } else {
    xgrow = xg + (size_t)b*SS*512;
    xv = xgrow[tid];
  }
  if (tid < 128) h_s[tid] = 0.f;
  float cstate = 0.f, hsum = 0.f;
  __syncthreads();

  for (int t=0;t<SS;t++) {
    float hv0 = h_s[lane];          // conflict-free ds_read_b32
    float hv1 = h_s[64+lane];
    float nxv = 0.f;
    if (MODE==0) {                  // prefetch next x_t
      int tn = (t < SS-1) ? (t+1) : t;
      nxv = xgrow[(size_t)tn*512 + tid];
    }
    float a0=0.f,a1=0.f,a2=0.f,a3=0.f;
    #pragma unroll
    for (int k=0;k<64;k+=2) {
      a0 += bcast_lane(hv0, k)   * w[k];
      a1 += bcast_lane(hv0, k+1) * w[k+1];
      a2 += bcast_lane(hv1, k)   * w[64+k];
      a3 += bcast_lane(hv1, k+1) * w[64+k+1];
    }
    float s = (a0+a1)+(a2+a3) + xv;
    int gid = tid >> 7;                         // wave-uniform gate id
    float act = (gid==2) ? tanhf(s) : 1.0f/(1.0f+expf(-s));
    act_s[tid] = act;
    __syncthreads();
    if (tid < 128) {
      float i_ = act_s[tid], f_ = act_s[128+tid], g_ = act_s[256+tid], o_ = act_s[384+tid];
      cstate = f_*cstate + i_*g_;
      float hh = o_*tanhf(cstate);
      h_s[tid] = hh;
      if (MODE==0) {
        hsum += hh;
      } else {
        size_t row = (size_t)b*SS + t;
        __hip_bfloat16 hi = __float2bfloat16(hh);
        float rem = hh - __bfloat162float(hi);
        ahi[row*HH + tid] = hi;
        alo[row*HH + tid] = __float2bfloat16(rem);
      }
    }
    if (MODE==0) xv = nxv;
    __syncthreads();
  }
  if (MODE==0 && tid < 128) hmean[b*HH + tid] = hsum * (1.0f/512.0f);
}

// ---------------- graph branch (collapsed to scalar edge passes) ----------------
__global__ __launch_bounds__(256) void edge_deg_kernel(const int* __restrict__ dst, float* __restrict__ deg) {
  int i = blockIdx.x*256 + threadIdx.x;
  if (i < NEDGE) atomicAdd(&deg[dst[i]], 1.0f);
}
__global__ __launch_bounds__(256) void node_dinv_kernel(const float* __restrict__ deg, float* __restrict__ dinv) {
  int n = blockIdx.x*256 + threadIdx.x;
  if (n < NNODE) dinv[n] = 1.0f / sqrtf(deg[n] + 1.0f);
}
__global__ __launch_bounds__(256) void edge_s1_kernel(const int* __restrict__ src, const int* __restrict__ dst,
    const float* __restrict__ dinv, float* __restrict__ s1) {
  int i = blockIdx.x*256 + threadIdx.x;
  if (i < NEDGE) atomicAdd(&s1[src[i]], dinv[dst[i]]);
}
__global__ __launch_bounds__(256) void node_c_kernel(const float* __restrict__ dinv, const float* __restrict__ s1,
    float* __restrict__ cc, float* __restrict__ csum) {
  __shared__ float red[256];
  int tid = threadIdx.x;
  int n = blockIdx.x*256 + tid;
  float v = 0.f;
  if (n < NNODE) { float d = dinv[n]; v = d*s1[n] + d*d; cc[n] = v; }
  red[tid] = v; __syncthreads();
  for (int sfl=128; sfl>0; sfl>>=1) { if (tid < sfl) red[tid] += red[tid+sfl]; __syncthreads(); }
  if (tid==0) atomicAdd(csum, red[0]);
}
__global__ __launch_bounds__(256) void edge_s2_kernel(const int* __restrict__ src, const int* __restrict__ dst,
    const float* __restrict__ dinv, const float* __restrict__ cc, float* __restrict__ s2) {
  int i = blockIdx.x*256 + threadIdx.x;
  if (i < NEDGE) { int d = dst[i]; atomicAdd(&s2[src[i]], cc[d]*dinv[d]); }
}
__global__ __launch_bounds__(256) void node_e_kernel(const float* __restrict__ dinv, const float* __restrict__ s2,
    const float* __restrict__ cc, float* __restrict__ ee) {
  int n = blockIdx.x*256 + threadIdx.x;
  if (n < NNODE) { float d = dinv[n]; ee[n] = d*s2[n] + cc[n]*d*d; }
}
__global__ __launch_bounds__(256) void gvec_kernel(const int* __restrict__ nids, const float* __restrict__ emb,
    const float* __restrict__ ee, float* __restrict__ gvec) {
  __shared__ float red[256];
  int tid = threadIdx.x;
  int j = tid & 127, sub = tid >> 7;
  float acc = 0.f;
  for (int n = blockIdx.x*2 + sub; n < NNODE; n += gridDim.x*2) {
    acc += ee[n] * emb[(size_t)nids[n]*HH + j];
  }
  red[tid] = acc; __syncthreads();
  if (tid < 128) atomicAdd(&gvec[j], red[tid] + red[tid+128]);
}
__global__ void graph_final_kernel(const float* __restrict__ gvec, const float* __restrict__ csum,
    const float* __restrict__ W1, const float* __restrict__ b1,
    const float* __restrict__ W2, const float* __restrict__ b2, float* __restrict__ mvec) {
  __shared__ float gs[128], v1[128];
  int j = threadIdx.x;
  gs[j] = gvec[j];
  __syncthreads();
  float a = 0.f;
  for (int k=0;k<128;k++) a += gs[k]*W1[j*128+k];
  v1[j] = a + csum[0]*b1[j];
  __syncthreads();
  float a2 = 0.f;
  for (int k=0;k<128;k++) a2 += v1[k]*W2[j*128+k];
  mvec[j] = a2 * (1.0f/(float)NNODE) + b2[j];
}

// ---------------- fusion ----------------
__global__ __launch_bounds__(512) void fusion_kernel(const float* __restrict__ hmean, const float* __restrict__ mvec,
    const float* __restrict__ Wf, const float* __restrict__ bfv,
    const float* __restrict__ Wihd, const float* __restrict__ bd, float* __restrict__ xgdec)
{
  __shared__ float comb[256];
  __shared__ float fus[128];
  int b = blockIdx.x, tid = threadIdx.x;
  if (tid < 128) comb[tid] = hmean[b*128 + tid];
  else if (tid < 256) comb[tid] = mvec[tid - 128];
  __syncthreads();
  if (tid < 128) {
    float a = 0.f;
    for (int k=0;k<256;k++) a += comb[k]*Wf[tid*256+k];
    fus[tid] = a + bfv[tid];
  }
  __syncthreads();
  float a = 0.f;
  for (int k=0;k<128;k++) a += fus[k]*Wihd[tid*128+k];
  xgdec[b*512 + tid] = a + bd[tid];
}

// ---------------- split fp32 -> (bf16 hi, bf16 lo) ----------------
__global__ __launch_bounds__(256) void split_bf16_kernel(const float* __restrict__ x,
    __hip_bfloat16* __restrict__ hi, __hip_bfloat16* __restrict__ lo, int n4) {
  int i = blockIdx.x*256 + threadIdx.x;
  if (i >= n4) return;
  float4 v = *(const float4*)&x[i*4];
  float vv[4] = {v.x, v.y, v.z, v.w};
  #pragma unroll
  for (int k=0;k<4;k++) {
    __hip_bfloat16 h = __float2bfloat16(vv[k]);
    hi[i*4+k] = h;
    lo[i*4+k] = __float2bfloat16(vv[k] - __bfloat162float(h));
  }
}

// ---------------- output GEMM: [4096,128] @ Wo^T -> [4096,32000], split-bf16 MFMA ----------------
__global__ __launch_bounds__(256) void out_gemm_kernel(
    const __hip_bfloat16* __restrict__ Ahi, const __hip_bfloat16* __restrict__ Alo,
    const __hip_bfloat16* __restrict__ Bhi, const __hip_bfloat16* __restrict__ Blo,
    const float* __restrict__ bo, float* __restrict__ out)
{
  __shared__ __align__(16) short smem[4*64*128];   // 4 planes x 16KB = 64KB
  const int tid = threadIdx.x;
  const int bid = blockIdx.x;
  const int mblk = bid & 63;
  const int nblk = bid >> 6;
  const short* srcs[4] = {
    (const short*)Ahi + (size_t)mblk*64*HH,
    (const short*)Alo + (size_t)mblk*64*HH,
    (const short*)Bhi + (size_t)nblk*64*HH,
    (const short*)Blo + (size_t)nblk*64*HH };
  const int wuni  = (tid >> 6) * 1024;
  const int lbyte = (tid & 63) * 16;
  #pragma unroll
  for (int p=0;p<4;p++) {
    #pragma unroll
    for (int it=0; it<4; it++) {
      int off  = it*4096 + wuni + lbyte;
      int row  = off >> 8;
      int soff = off ^ ((row & 15) << 4);
      __builtin_amdgcn_global_load_lds(
        (const __attribute__((address_space(1))) void*)((const char*)srcs[p] + soff),
        (__attribute__((address_space(3))) void*)((char*)smem + p*16384 + it*4096 + wuni),
        16, 0, 0);
    }
  }
  __syncthreads();

  const int lane = tid & 63;
  const int wid  = tid >> 6;
  const int wm = wid >> 1, wn = wid & 1;
  const int l15 = lane & 15, l4 = lane >> 4;

  f32x4 acc[2][2] = {};
  #pragma unroll
  for (int s=0;s<4;s++) {
    s16x8 ah[2], al[2], bh[2], bl[2];
    #pragma unroll
    for (int q=0;q<2;q++) {
      int ra   = wm*32 + q*16 + l15;
      int offa = (ra*256 + s*64 + l4*16) ^ ((ra & 15) << 4);
      ah[q] = *(const s16x8*)((const char*)smem + offa);
      al[q] = *(const s16x8*)((const char*)smem + 16384 + offa);
      int rb   = wn*32 + q*16 + l15;
      int offb = (rb*256 + s*64 + l4*16) ^ ((rb & 15) << 4);
      bh[q] = *(const s16x8*)((const char*)smem + 32768 + offb);
      bl[q] = *(const s16x8*)((const char*)smem + 49152 + offb);
    }
    #pragma unroll
    for (int mi=0;mi<2;mi++) {
      #pragma unroll
      for (int ni=0;ni<2;ni++) {
        acc[mi][ni] = __builtin_amdgcn_mfma_f32_16x16x32_bf16(ah[mi], bh[ni], acc[mi][ni], 0,0,0);
        acc[mi][ni] = __builtin_amdgcn_mfma_f32_16x16x32_bf16(ah[mi], bl[ni], acc[mi][ni], 0,0,0);
        acc[mi][ni] = __builtin_amdgcn_mfma_f32_16x16x32_bf16(al[mi], bh[ni], acc[mi][ni], 0,0,0);
      }
    }
  }
  const int m0 = mblk*64 + wm*32;
  const int n0 = nblk*64 + wn*32;
  #pragma unroll
  for (int ni=0;ni<2;ni++) {
    int col = n0 + ni*16 + l15;
    float bov = bo[col];
    #pragma unroll
    for (int mi=0;mi<2;mi++) {
      #pragma unroll
      for (int r=0;r<4;r++) {
        int row = m0 + mi*16 + l4*4 + r;
        out[(size_t)row*VV + col] = acc[mi][ni][r] + bov;
      }
    }
  }
}

// ---------------- launch ----------------
extern "C" void kernel_launch(void* const* d_in, const int* in_sizes, int n_in,
                              void* d_out, int out_size, void* d_ws, size_t ws_size,
                              hipStream_t stream)
{
  (void)in_sizes; (void)n_in; (void)out_size; (void)ws_size;
  const int*   jin   = (const int*)d_in[0];
  const int*   nids  = (const int*)d_in[1];
  const int*   esrc  = (const int*)d_in[2];
  const int*   edst  = esrc + NEDGE;
  const float* emb   = (const float*)d_in[3];
  const float* WihE  = (const float*)d_in[4];
  const float* WhhE  = (const float*)d_in[5];
  const float* bE    = (const float*)d_in[6];
  const float* W1    = (const float*)d_in[7];
  const float* b1    = (const float*)d_in[8];
  const float* W2    = (const float*)d_in[9];
  const float* b2    = (const float*)d_in[10];
  const float* Wf    = (const float*)d_in[11];
  const float* bfv   = (const float*)d_in[12];
  const float* WihD  = (const float*)d_in[13];
  const float* WhhD  = (const float*)d_in[14];
  const float* bD    = (const float*)d_in[15];
  const float* Wo    = (const float*)d_in[16];
  const float* bo    = (const float*)d_in[17];
  float* out = (float*)d_out;

  char* ws = (char*)d_ws;
  size_t off = 0;
  auto alloc = [&](size_t bytes) { size_t o = off; off = (off + bytes + 255) & ~(size_t)255; return o; };

  float* deg  = (float*)(ws + alloc(NNODE*4));
  float* s1   = (float*)(ws + alloc(NNODE*4));
  float* s2   = (float*)(ws + alloc(NNODE*4));
  float* gvec = (float*)(ws + alloc(128*4));
  float* csum = (float*)(ws + alloc(4));
  size_t zero_bytes = off;
  float* dinv = (float*)(ws + alloc(NNODE*4));
  float* cc   = (float*)(ws + alloc(NNODE*4));
  float* ee   = (float*)(ws + alloc(NNODE*4));
  float* mvec = (float*)(ws + alloc(128*4));
  float* hmean= (float*)(ws + alloc(BB*HH*4));
  float* xgdec= (float*)(ws + alloc(BB*512*4));
  float* xgenc= (float*)(ws + alloc((size_t)BB*SS*512*4));
  __hip_bfloat16* Ahi = (__hip_bfloat16*)(ws + alloc((size_t)BB*SS*HH*2));
  __hip_bfloat16* Alo = (__hip_bfloat16*)(ws + alloc((size_t)BB*SS*HH*2));
  __hip_bfloat16* Bhi = (__hip_bfloat16*)(ws + alloc((size_t)VV*HH*2));
  __hip_bfloat16* Blo = (__hip_bfloat16*)(ws + alloc((size_t)VV*HH*2));

  hipMemsetAsync(ws, 0, zero_bytes, stream);

  // sequence branch
  xg_enc_kernel<<<dim3((BB*SS)/8), dim3(256), 0, stream>>>(jin, emb, WihE, bE, xgenc);
  lstm_scan_kernel<0><<<dim3(BB), dim3(512), 0, stream>>>(xgenc, WhhE, hmean, nullptr, nullptr);

  // graph branch (collapsed)
  edge_deg_kernel<<<dim3((NEDGE+255)/256), dim3(256), 0, stream>>>(edst, deg);
  node_dinv_kernel<<<dim3((NNODE+255)/256), dim3(256), 0, stream>>>(deg, dinv);
  edge_s1_kernel<<<dim3((NEDGE+255)/256), dim3(256), 0, stream>>>(esrc, edst, dinv, s1);
  node_c_kernel<<<dim3((NNODE+255)/256), dim3(256), 0, stream>>>(dinv, s1, cc, csum);
  edge_s2_kernel<<<dim3((NEDGE+255)/256), dim3(256), 0, stream>>>(esrc, edst, dinv, cc, s2);
  node_e_kernel<<<dim3((NNODE+255)/256), dim3(256), 0, stream>>>(dinv, s2, cc, ee);
  gvec_kernel<<<dim3(256), dim3(256), 0, stream>>>(nids, emb, ee, gvec);
  graph_final_kernel<<<dim3(1), dim3(128), 0, stream>>>(gvec, csum, W1, b1, W2, b2, mvec);

  // fusion + decoder
  fusion_kernel<<<dim3(BB), dim3(512), 0, stream>>>(hmean, mvec, Wf, bfv, WihD, bD, xgdec);
  lstm_scan_kernel<1><<<dim3(BB), dim3(512), 0, stream>>>(xgdec, WhhD, nullptr, Ahi, Alo);

  // output projection
  split_bf16_kernel<<<dim3((VV*HH/4+255)/256), dim3(256), 0, stream>>>(Wo, Bhi, Blo, VV*HH/4);
  out_gemm_kernel<<<dim3(64*(VV/64)), dim3(256), 0, stream>>>(Ahi, Alo, Bhi, Blo, bo, out);
}

// Round 4
// 1340.333 us; speedup vs baseline: 1.6944x; 1.2885x over previous
//
#include <hip/hip_runtime.h>
#include <hip/hip_bf16.h>
#include <stdint.h>

#define VV 32000
#define HH 128
#define BB 8
#define SS 512
#define NNODE 50000
#define NEDGE 600000

typedef __attribute__((ext_vector_type(8))) short s16x8;
typedef __attribute__((ext_vector_type(4))) float f32x4;

// ---------------- embedding gather + encoder input-gate GEMM ----------------
__global__ __launch_bounds__(256) void xg_enc_kernel(
    const int* __restrict__ jin, const float* __restrict__ emb,
    const float* __restrict__ Wih, const float* __restrict__ bvec,
    float* __restrict__ xg)
{
  __shared__ __align__(16) float arow[8][128];
  const int tid = threadIdx.x, blk = blockIdx.x;
  {
    int r = tid >> 5, c = (tid & 31) << 2;
    int tok = jin[blk*8 + r];
    *(float4*)&arow[r][c] = *(const float4*)&emb[(size_t)tok*HH + c];
  }
  __syncthreads();
  const int g0 = tid * 2;
  const float* w0 = Wih + (size_t)g0*HH;
  const float* w1 = w0 + HH;
  float acc0[8], acc1[8];
  #pragma unroll
  for (int r=0;r<8;r++){ acc0[r]=0.f; acc1[r]=0.f; }
  for (int k=0;k<HH;k+=4) {
    float4 wa = *(const float4*)&w0[k];
    float4 wb = *(const float4*)&w1[k];
    #pragma unroll
    for (int r=0;r<8;r++) {
      float4 av = *(const float4*)&arow[r][k];
      acc0[r] += av.x*wa.x + av.y*wa.y + av.z*wa.z + av.w*wa.w;
      acc1[r] += av.x*wb.x + av.y*wb.y + av.z*wb.z + av.w*wb.w;
    }
  }
  float bb0 = bvec[g0], bb1 = bvec[g0+1];
  #pragma unroll
  for (int r=0;r<8;r++) {
    size_t row = (size_t)blk*8 + r;
    xg[row*512 + g0]     = acc0[r] + bb0;
    xg[row*512 + g0 + 1] = acc1[r] + bb1;
  }
}

// ---------------- LSTM scan: 1 workgroup (512 thr) per batch element ----------------
// Thread t owns gate row g = t (i:0-127, f:128-255, g:256-383, o:384-511).
// Weights: 32 f32x4 SSA values (NEVER address-taken -> SROA keeps them in
// registers) + asm volatile pin (opaque -> no rematerialization). ~165 VGPRs,
// under the 256 cap at 2 waves/SIMD.
template<int MODE>
__global__ __launch_bounds__(512, 2) void lstm_scan_kernel(
    const float* __restrict__ xg, const float* __restrict__ Whh,
    float* __restrict__ hmean,
    __hip_bfloat16* __restrict__ ahi, __hip_bfloat16* __restrict__ alo)
{
  __shared__ __align__(16) float h_s[128];
  __shared__ float act_s[512];
  const int b = blockIdx.x, tid = threadIdx.x;

  const f32x4* Wrow = (const f32x4*)(Whh + (size_t)tid*HH);
  f32x4 w[32];
  #pragma unroll
  for (int k=0;k<32;k++) w[k] = Wrow[k];        // clean SSA vector loads
  #pragma unroll
  for (int k=0;k<32;k++) asm volatile("" : "+v"(w[k]));  // pin: no remat

  float xv;
  const float* xgrow = nullptr;
  if (MODE==1) {
    xv = xg[b*512 + tid];
  } else {
    xgrow = xg + (size_t)b*SS*512;
    xv = xgrow[tid];
  }
  if (tid < 128) h_s[tid] = 0.f;
  float cstate = 0.f, hsum = 0.f;
  __syncthreads();

  for (int t=0;t<SS;t++) {
    float nxv = 0.f;
    if (MODE==0) {                  // prefetch next x_t
      int tn = (t < SS-1) ? (t+1) : t;
      nxv = xgrow[(size_t)tn*512 + tid];
    }
    float a0=0.f,a1=0.f,a2=0.f,a3=0.f;
    #pragma unroll
    for (int k=0;k<32;k++) {
      f32x4 hv = *(const f32x4*)&h_s[k*4];   // wave-uniform -> LDS broadcast
      a0 += w[k].x*hv.x; a1 += w[k].y*hv.y;
      a2 += w[k].z*hv.z; a3 += w[k].w*hv.w;
    }
    float s = (a0+a1)+(a2+a3) + xv;
    int gid = tid >> 7;                         // wave-uniform gate id
    float act = (gid==2) ? tanhf(s) : 1.0f/(1.0f+expf(-s));
    act_s[tid] = act;
    __syncthreads();
    if (tid < 128) {
      float i_ = act_s[tid], f_ = act_s[128+tid], g_ = act_s[256+tid], o_ = act_s[384+tid];
      cstate = f_*cstate + i_*g_;
      float hh = o_*tanhf(cstate);
      h_s[tid] = hh;
      if (MODE==0) {
        hsum += hh;
      } else {
        size_t row = (size_t)b*SS + t;
        __hip_bfloat16 hi = __float2bfloat16(hh);
        float rem = hh - __bfloat162float(hi);
        ahi[row*HH + tid] = hi;
        alo[row*HH + tid] = __float2bfloat16(rem);
      }
    }
    if (MODE==0) xv = nxv;
    __syncthreads();
  }
  if (MODE==0 && tid < 128) hmean[b*HH + tid] = hsum * (1.0f/512.0f);
}

// ---------------- graph branch (collapsed to scalar edge passes) ----------------
__global__ __launch_bounds__(256) void edge_deg_kernel(const int* __restrict__ dst, float* __restrict__ deg) {
  int i = blockIdx.x*256 + threadIdx.x;
  if (i < NEDGE) atomicAdd(&deg[dst[i]], 1.0f);
}
__global__ __launch_bounds__(256) void node_dinv_kernel(const float* __restrict__ deg, float* __restrict__ dinv) {
  int n = blockIdx.x*256 + threadIdx.x;
  if (n < NNODE) dinv[n] = 1.0f / sqrtf(deg[n] + 1.0f);
}
__global__ __launch_bounds__(256) void edge_s1_kernel(const int* __restrict__ src, const int* __restrict__ dst,
    const float* __restrict__ dinv, float* __restrict__ s1) {
  int i = blockIdx.x*256 + threadIdx.x;
  if (i < NEDGE) atomicAdd(&s1[src[i]], dinv[dst[i]]);
}
__global__ __launch_bounds__(256) void node_c_kernel(const float* __restrict__ dinv, const float* __restrict__ s1,
    float* __restrict__ cc, float* __restrict__ csum) {
  __shared__ float red[256];
  int tid = threadIdx.x;
  int n = blockIdx.x*256 + tid;
  float v = 0.f;
  if (n < NNODE) { float d = dinv[n]; v = d*s1[n] + d*d; cc[n] = v; }
  red[tid] = v; __syncthreads();
  for (int sfl=128; sfl>0; sfl>>=1) { if (tid < sfl) red[tid] += red[tid+sfl]; __syncthreads(); }
  if (tid==0) atomicAdd(csum, red[0]);
}
__global__ __launch_bounds__(256) void edge_s2_kernel(const int* __restrict__ src, const int* __restrict__ dst,
    const float* __restrict__ dinv, const float* __restrict__ cc, float* __restrict__ s2) {
  int i = blockIdx.x*256 + threadIdx.x;
  if (i < NEDGE) { int d = dst[i]; atomicAdd(&s2[src[i]], cc[d]*dinv[d]); }
}
__global__ __launch_bounds__(256) void node_e_kernel(const float* __restrict__ dinv, const float* __restrict__ s2,
    const float* __restrict__ cc, float* __restrict__ ee) {
  int n = blockIdx.x*256 + threadIdx.x;
  if (n < NNODE) { float d = dinv[n]; ee[n] = d*s2[n] + cc[n]*d*d; }
}
__global__ __launch_bounds__(256) void gvec_kernel(const int* __restrict__ nids, const float* __restrict__ emb,
    const float* __restrict__ ee, float* __restrict__ gvec) {
  __shared__ float red[256];
  int tid = threadIdx.x;
  int j = tid & 127, sub = tid >> 7;
  float acc = 0.f;
  for (int n = blockIdx.x*2 + sub; n < NNODE; n += gridDim.x*2) {
    acc += ee[n] * emb[(size_t)nids[n]*HH + j];
  }
  red[tid] = acc; __syncthreads();
  if (tid < 128) atomicAdd(&gvec[j], red[tid] + red[tid+128]);
}
__global__ void graph_final_kernel(const float* __restrict__ gvec, const float* __restrict__ csum,
    const float* __restrict__ W1, const float* __restrict__ b1,
    const float* __restrict__ W2, const float* __restrict__ b2, float* __restrict__ mvec) {
  __shared__ float gs[128], v1[128];
  int j = threadIdx.x;
  gs[j] = gvec[j];
  __syncthreads();
  float a = 0.f;
  for (int k=0;k<128;k++) a += gs[k]*W1[j*128+k];
  v1[j] = a + csum[0]*b1[j];
  __syncthreads();
  float a2 = 0.f;
  for (int k=0;k<128;k++) a2 += v1[k]*W2[j*128+k];
  mvec[j] = a2 * (1.0f/(float)NNODE) + b2[j];
}

// ---------------- fusion ----------------
__global__ __launch_bounds__(512) void fusion_kernel(const float* __restrict__ hmean, const float* __restrict__ mvec,
    const float* __restrict__ Wf, const float* __restrict__ bfv,
    const float* __restrict__ Wihd, const float* __restrict__ bd, float* __restrict__ xgdec)
{
  __shared__ float comb[256];
  __shared__ float fus[128];
  int b = blockIdx.x, tid = threadIdx.x;
  if (tid < 128) comb[tid] = hmean[b*128 + tid];
  else if (tid < 256) comb[tid] = mvec[tid - 128];
  __syncthreads();
  if (tid < 128) {
    float a = 0.f;
    for (int k=0;k<256;k++) a += comb[k]*Wf[tid*256+k];
    fus[tid] = a + bfv[tid];
  }
  __syncthreads();
  float a = 0.f;
  for (int k=0;k<128;k++) a += fus[k]*Wihd[tid*128+k];
  xgdec[b*512 + tid] = a + bd[tid];
}

// ---------------- split fp32 -> (bf16 hi, bf16 lo) ----------------
__global__ __launch_bounds__(256) void split_bf16_kernel(const float* __restrict__ x,
    __hip_bfloat16* __restrict__ hi, __hip_bfloat16* __restrict__ lo, int n4) {
  int i = blockIdx.x*256 + threadIdx.x;
  if (i >= n4) return;
  float4 v = *(const float4*)&x[i*4];
  float vv[4] = {v.x, v.y, v.z, v.w};
  #pragma unroll
  for (int k=0;k<4;k++) {
    __hip_bfloat16 h = __float2bfloat16(vv[k]);
    hi[i*4+k] = h;
    lo[i*4+k] = __float2bfloat16(vv[k] - __bfloat162float(h));
  }
}

// ---------------- output GEMM: [4096,128] @ Wo^T -> [4096,32000], split-bf16 MFMA ----------------
__global__ __launch_bounds__(256) void out_gemm_kernel(
    const __hip_bfloat16* __restrict__ Ahi, const __hip_bfloat16* __restrict__ Alo,
    const __hip_bfloat16* __restrict__ Bhi, const __hip_bfloat16* __restrict__ Blo,
    const float* __restrict__ bo, float* __restrict__ out)
{
  __shared__ __align__(16) short smem[4*64*128];   // 4 planes x 16KB = 64KB
  const int tid = threadIdx.x;
  const int bid = blockIdx.x;
  const int mblk = bid & 63;
  const int nblk = bid >> 6;
  const short* srcs[4] = {
    (const short*)Ahi + (size_t)mblk*64*HH,
    (const short*)Alo + (size_t)mblk*64*HH,
    (const short*)Bhi + (size_t)nblk*64*HH,
    (const short*)Blo + (size_t)nblk*64*HH };
  const int wuni  = (tid >> 6) * 1024;
  const int lbyte = (tid & 63) * 16;
  #pragma unroll
  for (int p=0;p<4;p++) {
    #pragma unroll
    for (int it=0; it<4; it++) {
      int off  = it*4096 + wuni + lbyte;
      int row  = off >> 8;
      int soff = off ^ ((row & 15) << 4);
      __builtin_amdgcn_global_load_lds(
        (const __attribute__((address_space(1))) void*)((const char*)srcs[p] + soff),
        (__attribute__((address_space(3))) void*)((char*)smem + p*16384 + it*4096 + wuni),
        16, 0, 0);
    }
  }
  __syncthreads();

  const int lane = tid & 63;
  const int wid  = tid >> 6;
  const int wm = wid >> 1, wn = wid & 1;
  const int l15 = lane & 15, l4 = lane >> 4;

  f32x4 acc[2][2] = {};
  #pragma unroll
  for (int s=0;s<4;s++) {
    s16x8 ah[2], al[2], bh[2], bl[2];
    #pragma unroll
    for (int q=0;q<2;q++) {
      int ra   = wm*32 + q*16 + l15;
      int offa = (ra*256 + s*64 + l4*16) ^ ((ra & 15) << 4);
      ah[q] = *(const s16x8*)((const char*)smem + offa);
      al[q] = *(const s16x8*)((const char*)smem + 16384 + offa);
      int rb   = wn*32 + q*16 + l15;
      int offb = (rb*256 + s*64 + l4*16) ^ ((rb & 15) << 4);
      bh[q] = *(const s16x8*)((const char*)smem + 32768 + offb);
      bl[q] = *(const s16x8*)((const char*)smem + 49152 + offb);
    }
    #pragma unroll
    for (int mi=0;mi<2;mi++) {
      #pragma unroll
      for (int ni=0;ni<2;ni++) {
        acc[mi][ni] = __builtin_amdgcn_mfma_f32_16x16x32_bf16(ah[mi], bh[ni], acc[mi][ni], 0,0,0);
        acc[mi][ni] = __builtin_amdgcn_mfma_f32_16x16x32_bf16(ah[mi], bl[ni], acc[mi][ni], 0,0,0);
        acc[mi][ni] = __builtin_amdgcn_mfma_f32_16x16x32_bf16(al[mi], bh[ni], acc[mi][ni], 0,0,0);
      }
    }
  }
  const int m0 = mblk*64 + wm*32;
  const int n0 = nblk*64 + wn*32;
  #pragma unroll
  for (int ni=0;ni<2;ni++) {
    int col = n0 + ni*16 + l15;
    float bov = bo[col];
    #pragma unroll
    for (int mi=0;mi<2;mi++) {
      #pragma unroll
      for (int r=0;r<4;r++) {
        int row = m0 + mi*16 + l4*4 + r;
        out[(size_t)row*VV + col] = acc[mi][ni][r] + bov;
      }
    }
  }
}

// ---------------- launch ----------------
extern "C" void kernel_launch(void* const* d_in, const int* in_sizes, int n_in,
                              void* d_out, int out_size, void* d_ws, size_t ws_size,
                              hipStream_t stream)
{
  (void)in_sizes; (void)n_in; (void)out_size; (void)ws_size;
  const int*   jin   = (const int*)d_in[0];
  const int*   nids  = (const int*)d_in[1];
  const int*   esrc  = (const int*)d_in[2];
  const int*   edst  = esrc + NEDGE;
  const float* emb   = (const float*)d_in[3];
  const float* WihE  = (const float*)d_in[4];
  const float* WhhE  = (const float*)d_in[5];
  const float* bE    = (const float*)d_in[6];
  const float* W1    = (const float*)d_in[7];
  const float* b1    = (const float*)d_in[8];
  const float* W2    = (const float*)d_in[9];
  const float* b2    = (const float*)d_in[10];
  const float* Wf    = (const float*)d_in[11];
  const float* bfv   = (const float*)d_in[12];
  const float* WihD  = (const float*)d_in[13];
  const float* WhhD  = (const float*)d_in[14];
  const float* bD    = (const float*)d_in[15];
  const float* Wo    = (const float*)d_in[16];
  const float* bo    = (const float*)d_in[17];
  float* out = (float*)d_out;

  char* ws = (char*)d_ws;
  size_t off = 0;
  auto alloc = [&](size_t bytes) { size_t o = off; off = (off + bytes + 255) & ~(size_t)255; return o; };

  float* deg  = (float*)(ws + alloc(NNODE*4));
  float* s1   = (float*)(ws + alloc(NNODE*4));
  float* s2   = (float*)(ws + alloc(NNODE*4));
  float* gvec = (float*)(ws + alloc(128*4));
  float* csum = (float*)(ws + alloc(4));
  size_t zero_bytes = off;
  float* dinv = (float*)(ws + alloc(NNODE*4));
  float* cc   = (float*)(ws + alloc(NNODE*4));
  float* ee   = (float*)(ws + alloc(NNODE*4));
  float* mvec = (float*)(ws + alloc(128*4));
  float* hmean= (float*)(ws + alloc(BB*HH*4));
  float* xgdec= (float*)(ws + alloc(BB*512*4));
  float* xgenc= (float*)(ws + alloc((size_t)BB*SS*512*4));
  __hip_bfloat16* Ahi = (__hip_bfloat16*)(ws + alloc((size_t)BB*SS*HH*2));
  __hip_bfloat16* Alo = (__hip_bfloat16*)(ws + alloc((size_t)BB*SS*HH*2));
  __hip_bfloat16* Bhi = (__hip_bfloat16*)(ws + alloc((size_t)VV*HH*2));
  __hip_bfloat16* Blo = (__hip_bfloat16*)(ws + alloc((size_t)VV*HH*2));

  hipMemsetAsync(ws, 0, zero_bytes, stream);

  // sequence branch
  xg_enc_kernel<<<dim3((BB*SS)/8), dim3(256), 0, stream>>>(jin, emb, WihE, bE, xgenc);
  lstm_scan_kernel<0><<<dim3(BB), dim3(512), 0, stream>>>(xgenc, WhhE, hmean, nullptr, nullptr);

  // graph branch (collapsed)
  edge_deg_kernel<<<dim3((NEDGE+255)/256), dim3(256), 0, stream>>>(edst, deg);
  node_dinv_kernel<<<dim3((NNODE+255)/256), dim3(256), 0, stream>>>(deg, dinv);
  edge_s1_kernel<<<dim3((NEDGE+255)/256), dim3(256), 0, stream>>>(esrc, edst, dinv, s1);
  node_c_kernel<<<dim3((NNODE+255)/256), dim3(256), 0, stream>>>(dinv, s1, cc, csum);
  edge_s2_kernel<<<dim3((NEDGE+255)/256), dim3(256), 0, stream>>>(esrc, edst, dinv, cc, s2);
  node_e_kernel<<<dim3((NNODE+255)/256), dim3(256), 0, stream>>>(dinv, s2, cc, ee);
  gvec_kernel<<<dim3(256), dim3(256), 0, stream>>>(nids, emb, ee, gvec);
  graph_final_kernel<<<dim3(1), dim3(128), 0, stream>>>(gvec, csum, W1, b1, W2, b2, mvec);

  // fusion + decoder
  fusion_kernel<<<dim3(BB), dim3(512), 0, stream>>>(hmean, mvec, Wf, bfv, WihD, bD, xgdec);
  lstm_scan_kernel<1><<<dim3(BB), dim3(512), 0, stream>>>(xgdec, WhhD, nullptr, Ahi, Alo);

  // output projection
  split_bf16_kernel<<<dim3((VV*HH/4+255)/256), dim3(256), 0, stream>>>(Wo, Bhi, Blo, VV*HH/4);
  out_gemm_kernel<<<dim3(64*(VV/64)), dim3(256), 0, stream>>>(Ahi, Alo, Bhi, Blo, bo, out);
}

// Round 5
// 1336.604 us; speedup vs baseline: 1.6991x; 1.0028x over previous
//
#include <hip/hip_runtime.h>
#include <hip/hip_bf16.h>
#include <stdint.h>

#define VV 32000
#define HH 128
#define BB 8
#define SS 512
#define NNODE 50000
#define NEDGE 600000

typedef __attribute__((ext_vector_type(8))) short s16x8;
typedef __attribute__((ext_vector_type(4))) float f32x4;

// ---------------- embedding gather + encoder input-gate GEMM ----------------
__global__ __launch_bounds__(256) void xg_enc_kernel(
    const int* __restrict__ jin, const float* __restrict__ emb,
    const float* __restrict__ Wih, const float* __restrict__ bvec,
    float* __restrict__ xg)
{
  __shared__ __align__(16) float arow[8][128];
  const int tid = threadIdx.x, blk = blockIdx.x;
  {
    int r = tid >> 5, c = (tid & 31) << 2;
    int tok = jin[blk*8 + r];
    *(float4*)&arow[r][c] = *(const float4*)&emb[(size_t)tok*HH + c];
  }
  __syncthreads();
  const int g0 = tid * 2;
  const float* w0 = Wih + (size_t)g0*HH;
  const float* w1 = w0 + HH;
  float acc0[8], acc1[8];
  #pragma unroll
  for (int r=0;r<8;r++){ acc0[r]=0.f; acc1[r]=0.f; }
  for (int k=0;k<HH;k+=4) {
    float4 wa = *(const float4*)&w0[k];
    float4 wb = *(const float4*)&w1[k];
    #pragma unroll
    for (int r=0;r<8;r++) {
      float4 av = *(const float4*)&arow[r][k];
      acc0[r] += av.x*wa.x + av.y*wa.y + av.z*wa.z + av.w*wa.w;
      acc1[r] += av.x*wb.x + av.y*wb.y + av.z*wb.z + av.w*wb.w;
    }
  }
  float bb0 = bvec[g0], bb1 = bvec[g0+1];
  #pragma unroll
  for (int r=0;r<8;r++) {
    size_t row = (size_t)blk*8 + r;
    xg[row*512 + g0]     = acc0[r] + bb0;
    xg[row*512 + g0 + 1] = acc1[r] + bb1;
  }
}

// ---------------- LSTM scan: 1 workgroup (512 thr) per batch element ----------------
// Thread t owns gate row g = t (i:0-127, f:128-255, g:256-383, o:384-511).
// KEY: amdgpu_waves_per_eu(2,2) pins the backend's occupancy TARGET at 2
// waves/EU (256-VGPR budget), so the scheduler/RA stops sinking/spilling the
// 128 weight floats to chase higher occupancy. Weights are clean SSA f32x4
// values (never address-taken) + asm pin (no rematerialization).
template<int MODE>
__global__ __launch_bounds__(512)
__attribute__((amdgpu_waves_per_eu(2, 2)))
void lstm_scan_kernel(
    const float* __restrict__ xg, const float* __restrict__ Whh,
    float* __restrict__ hmean,
    __hip_bfloat16* __restrict__ ahi, __hip_bfloat16* __restrict__ alo)
{
  __shared__ __align__(16) float h_s[128];
  __shared__ float act_s[512];
  const int b = blockIdx.x, tid = threadIdx.x;

  const f32x4* Wrow = (const f32x4*)(Whh + (size_t)tid*HH);
  f32x4 w[32];
  #pragma unroll
  for (int k=0;k<32;k++) w[k] = Wrow[k];        // clean SSA vector loads
  #pragma unroll
  for (int k=0;k<32;k++) asm volatile("" : "+v"(w[k]));  // pin: no remat

  float xv;
  const float* xgrow = nullptr;
  if (MODE==1) {
    xv = xg[b*512 + tid];
  } else {
    xgrow = xg + (size_t)b*SS*512;
    xv = xgrow[tid];
  }
  if (tid < 128) h_s[tid] = 0.f;
  float cstate = 0.f, hsum = 0.f;
  __syncthreads();

  for (int t=0;t<SS;t++) {
    float nxv = 0.f;
    if (MODE==0) {                  // prefetch next x_t
      int tn = (t < SS-1) ? (t+1) : t;
      nxv = xgrow[(size_t)tn*512 + tid];
    }
    float a0=0.f,a1=0.f,a2=0.f,a3=0.f;
    #pragma unroll
    for (int k=0;k<32;k++) {
      f32x4 hv = *(const f32x4*)&h_s[k*4];   // wave-uniform -> LDS broadcast
      a0 += w[k].x*hv.x; a1 += w[k].y*hv.y;
      a2 += w[k].z*hv.z; a3 += w[k].w*hv.w;
    }
    float s = (a0+a1)+(a2+a3) + xv;
    int gid = tid >> 7;                         // wave-uniform gate id
    float act = (gid==2) ? tanhf(s) : 1.0f/(1.0f+expf(-s));
    act_s[tid] = act;
    __syncthreads();
    if (tid < 128) {
      float i_ = act_s[tid], f_ = act_s[128+tid], g_ = act_s[256+tid], o_ = act_s[384+tid];
      cstate = f_*cstate + i_*g_;
      float hh = o_*tanhf(cstate);
      h_s[tid] = hh;
      if (MODE==0) {
        hsum += hh;
      } else {
        size_t row = (size_t)b*SS + t;
        __hip_bfloat16 hi = __float2bfloat16(hh);
        float rem = hh - __bfloat162float(hi);
        ahi[row*HH + tid] = hi;
        alo[row*HH + tid] = __float2bfloat16(rem);
      }
    }
    if (MODE==0) xv = nxv;
    __syncthreads();
  }
  if (MODE==0 && tid < 128) hmean[b*HH + tid] = hsum * (1.0f/512.0f);
}

// ---------------- graph branch (collapsed to scalar edge passes) ----------------
__global__ __launch_bounds__(256) void edge_deg_kernel(const int* __restrict__ dst, float* __restrict__ deg) {
  int i = blockIdx.x*256 + threadIdx.x;
  if (i < NEDGE) atomicAdd(&deg[dst[i]], 1.0f);
}
__global__ __launch_bounds__(256) void node_dinv_kernel(const float* __restrict__ deg, float* __restrict__ dinv) {
  int n = blockIdx.x*256 + threadIdx.x;
  if (n < NNODE) dinv[n] = 1.0f / sqrtf(deg[n] + 1.0f);
}
__global__ __launch_bounds__(256) void edge_s1_kernel(const int* __restrict__ src, const int* __restrict__ dst,
    const float* __restrict__ dinv, float* __restrict__ s1) {
  int i = blockIdx.x*256 + threadIdx.x;
  if (i < NEDGE) atomicAdd(&s1[src[i]], dinv[dst[i]]);
}
__global__ __launch_bounds__(256) void node_c_kernel(const float* __restrict__ dinv, const float* __restrict__ s1,
    float* __restrict__ cc, float* __restrict__ csum) {
  __shared__ float red[256];
  int tid = threadIdx.x;
  int n = blockIdx.x*256 + tid;
  float v = 0.f;
  if (n < NNODE) { float d = dinv[n]; v = d*s1[n] + d*d; cc[n] = v; }
  red[tid] = v; __syncthreads();
  for (int sfl=128; sfl>0; sfl>>=1) { if (tid < sfl) red[tid] += red[tid+sfl]; __syncthreads(); }
  if (tid==0) atomicAdd(csum, red[0]);
}
__global__ __launch_bounds__(256) void edge_s2_kernel(const int* __restrict__ src, const int* __restrict__ dst,
    const float* __restrict__ dinv, const float* __restrict__ cc, float* __restrict__ s2) {
  int i = blockIdx.x*256 + threadIdx.x;
  if (i < NEDGE) { int d = dst[i]; atomicAdd(&s2[src[i]], cc[d]*dinv[d]); }
}
__global__ __launch_bounds__(256) void node_e_kernel(const float* __restrict__ dinv, const float* __restrict__ s2,
    const float* __restrict__ cc, float* __restrict__ ee) {
  int n = blockIdx.x*256 + threadIdx.x;
  if (n < NNODE) { float d = dinv[n]; ee[n] = d*s2[n] + cc[n]*d*d; }
}
__global__ __launch_bounds__(256) void gvec_kernel(const int* __restrict__ nids, const float* __restrict__ emb,
    const float* __restrict__ ee, float* __restrict__ gvec) {
  __shared__ float red[256];
  int tid = threadIdx.x;
  int j = tid & 127, sub = tid >> 7;
  float acc = 0.f;
  for (int n = blockIdx.x*2 + sub; n < NNODE; n += gridDim.x*2) {
    acc += ee[n] * emb[(size_t)nids[n]*HH + j];
  }
  red[tid] = acc; __syncthreads();
  if (tid < 128) atomicAdd(&gvec[j], red[tid] + red[tid+128]);
}
__global__ void graph_final_kernel(const float* __restrict__ gvec, const float* __restrict__ csum,
    const float* __restrict__ W1, const float* __restrict__ b1,
    const float* __restrict__ W2, const float* __restrict__ b2, float* __restrict__ mvec) {
  __shared__ float gs[128], v1[128];
  int j = threadIdx.x;
  gs[j] = gvec[j];
  __syncthreads();
  float a = 0.f;
  for (int k=0;k<128;k++) a += gs[k]*W1[j*128+k];
  v1[j] = a + csum[0]*b1[j];
  __syncthreads();
  float a2 = 0.f;
  for (int k=0;k<128;k++) a2 += v1[k]*W2[j*128+k];
  mvec[j] = a2 * (1.0f/(float)NNODE) + b2[j];
}

// ---------------- fusion ----------------
__global__ __launch_bounds__(512) void fusion_kernel(const float* __restrict__ hmean, const float* __restrict__ mvec,
    const float* __restrict__ Wf, const float* __restrict__ bfv,
    const float* __restrict__ Wihd, const float* __restrict__ bd, float* __restrict__ xgdec)
{
  __shared__ float comb[256];
  __shared__ float fus[128];
  int b = blockIdx.x, tid = threadIdx.x;
  if (tid < 128) comb[tid] = hmean[b*128 + tid];
  else if (tid < 256) comb[tid] = mvec[tid - 128];
  __syncthreads();
  if (tid < 128) {
    float a = 0.f;
    for (int k=0;k<256;k++) a += comb[k]*Wf[tid*256+k];
    fus[tid] = a + bfv[tid];
  }
  __syncthreads();
  float a = 0.f;
  for (int k=0;k<128;k++) a += fus[k]*Wihd[tid*128+k];
  xgdec[b*512 + tid] = a + bd[tid];
}

// ---------------- split fp32 -> (bf16 hi, bf16 lo) ----------------
__global__ __launch_bounds__(256) void split_bf16_kernel(const float* __restrict__ x,
    __hip_bfloat16* __restrict__ hi, __hip_bfloat16* __restrict__ lo, int n4) {
  int i = blockIdx.x*256 + threadIdx.x;
  if (i >= n4) return;
  float4 v = *(const float4*)&x[i*4];
  float vv[4] = {v.x, v.y, v.z, v.w};
  #pragma unroll
  for (int k=0;k<4;k++) {
    __hip_bfloat16 h = __float2bfloat16(vv[k]);
    hi[i*4+k] = h;
    lo[i*4+k] = __float2bfloat16(vv[k] - __bfloat162float(h));
  }
}

// ---------------- output GEMM: [4096,128] @ Wo^T -> [4096,32000], split-bf16 MFMA ----------------
__global__ __launch_bounds__(256) void out_gemm_kernel(
    const __hip_bfloat16* __restrict__ Ahi, const __hip_bfloat16* __restrict__ Alo,
    const __hip_bfloat16* __restrict__ Bhi, const __hip_bfloat16* __restrict__ Blo,
    const float* __restrict__ bo, float* __restrict__ out)
{
  __shared__ __align__(16) short smem[4*64*128];   // 4 planes x 16KB = 64KB
  const int tid = threadIdx.x;
  const int bid = blockIdx.x;
  const int mblk = bid & 63;
  const int nblk = bid >> 6;
  const short* srcs[4] = {
    (const short*)Ahi + (size_t)mblk*64*HH,
    (const short*)Alo + (size_t)mblk*64*HH,
    (const short*)Bhi + (size_t)nblk*64*HH,
    (const short*)Blo + (size_t)nblk*64*HH };
  const int wuni  = (tid >> 6) * 1024;
  const int lbyte = (tid & 63) * 16;
  #pragma unroll
  for (int p=0;p<4;p++) {
    #pragma unroll
    for (int it=0; it<4; it++) {
      int off  = it*4096 + wuni + lbyte;
      int row  = off >> 8;
      int soff = off ^ ((row & 15) << 4);
      __builtin_amdgcn_global_load_lds(
        (const __attribute__((address_space(1))) void*)((const char*)srcs[p] + soff),
        (__attribute__((address_space(3))) void*)((char*)smem + p*16384 + it*4096 + wuni),
        16, 0, 0);
    }
  }
  __syncthreads();

  const int lane = tid & 63;
  const int wid  = tid >> 6;
  const int wm = wid >> 1, wn = wid & 1;
  const int l15 = lane & 15, l4 = lane >> 4;

  f32x4 acc[2][2] = {};
  #pragma unroll
  for (int s=0;s<4;s++) {
    s16x8 ah[2], al[2], bh[2], bl[2];
    #pragma unroll
    for (int q=0;q<2;q++) {
      int ra   = wm*32 + q*16 + l15;
      int offa = (ra*256 + s*64 + l4*16) ^ ((ra & 15) << 4);
      ah[q] = *(const s16x8*)((const char*)smem + offa);
      al[q] = *(const s16x8*)((const char*)smem + 16384 + offa);
      int rb   = wn*32 + q*16 + l15;
      int offb = (rb*256 + s*64 + l4*16) ^ ((rb & 15) << 4);
      bh[q] = *(const s16x8*)((const char*)smem + 32768 + offb);
      bl[q] = *(const s16x8*)((const char*)smem + 49152 + offb);
    }
    #pragma unroll
    for (int mi=0;mi<2;mi++) {
      #pragma unroll
      for (int ni=0;ni<2;ni++) {
        acc[mi][ni] = __builtin_amdgcn_mfma_f32_16x16x32_bf16(ah[mi], bh[ni], acc[mi][ni], 0,0,0);
        acc[mi][ni] = __builtin_amdgcn_mfma_f32_16x16x32_bf16(ah[mi], bl[ni], acc[mi][ni], 0,0,0);
        acc[mi][ni] = __builtin_amdgcn_mfma_f32_16x16x32_bf16(al[mi], bh[ni], acc[mi][ni], 0,0,0);
      }
    }
  }
  const int m0 = mblk*64 + wm*32;
  const int n0 = nblk*64 + wn*32;
  #pragma unroll
  for (int ni=0;ni<2;ni++) {
    int col = n0 + ni*16 + l15;
    float bov = bo[col];
    #pragma unroll
    for (int mi=0;mi<2;mi++) {
      #pragma unroll
      for (int r=0;r<4;r++) {
        int row = m0 + mi*16 + l4*4 + r;
        out[(size_t)row*VV + col] = acc[mi][ni][r] + bov;
      }
    }
  }
}

// ---------------- launch ----------------
extern "C" void kernel_launch(void* const* d_in, const int* in_sizes, int n_in,
                              void* d_out, int out_size, void* d_ws, size_t ws_size,
                              hipStream_t stream)
{
  (void)in_sizes; (void)n_in; (void)out_size; (void)ws_size;
  const int*   jin   = (const int*)d_in[0];
  const int*   nids  = (const int*)d_in[1];
  const int*   esrc  = (const int*)d_in[2];
  const int*   edst  = esrc + NEDGE;
  const float* emb   = (const float*)d_in[3];
  const float* WihE  = (const float*)d_in[4];
  const float* WhhE  = (const float*)d_in[5];
  const float* bE    = (const float*)d_in[6];
  const float* W1    = (const float*)d_in[7];
  const float* b1    = (const float*)d_in[8];
  const float* W2    = (const float*)d_in[9];
  const float* b2    = (const float*)d_in[10];
  const float* Wf    = (const float*)d_in[11];
  const float* bfv   = (const float*)d_in[12];
  const float* WihD  = (const float*)d_in[13];
  const float* WhhD  = (const float*)d_in[14];
  const float* bD    = (const float*)d_in[15];
  const float* Wo    = (const float*)d_in[16];
  const float* bo    = (const float*)d_in[17];
  float* out = (float*)d_out;

  char* ws = (char*)d_ws;
  size_t off = 0;
  auto alloc = [&](size_t bytes) { size_t o = off; off = (off + bytes + 255) & ~(size_t)255; return o; };

  float* deg  = (float*)(ws + alloc(NNODE*4));
  float* s1   = (float*)(ws + alloc(NNODE*4));
  float* s2   = (float*)(ws + alloc(NNODE*4));
  float* gvec = (float*)(ws + alloc(128*4));
  float* csum = (float*)(ws + alloc(4));
  size_t zero_bytes = off;
  float* dinv = (float*)(ws + alloc(NNODE*4));
  float* cc   = (float*)(ws + alloc(NNODE*4));
  float* ee   = (float*)(ws + alloc(NNODE*4));
  float* mvec = (float*)(ws + alloc(128*4));
  float* hmean= (float*)(ws + alloc(BB*HH*4));
  float* xgdec= (float*)(ws + alloc(BB*512*4));
  float* xgenc= (float*)(ws + alloc((size_t)BB*SS*512*4));
  __hip_bfloat16* Ahi = (__hip_bfloat16*)(ws + alloc((size_t)BB*SS*HH*2));
  __hip_bfloat16* Alo = (__hip_bfloat16*)(ws + alloc((size_t)BB*SS*HH*2));
  __hip_bfloat16* Bhi = (__hip_bfloat16*)(ws + alloc((size_t)VV*HH*2));
  __hip_bfloat16* Blo = (__hip_bfloat16*)(ws + alloc((size_t)VV*HH*2));

  hipMemsetAsync(ws, 0, zero_bytes, stream);

  // sequence branch
  xg_enc_kernel<<<dim3((BB*SS)/8), dim3(256), 0, stream>>>(jin, emb, WihE, bE, xgenc);
  lstm_scan_kernel<0><<<dim3(BB), dim3(512), 0, stream>>>(xgenc, WhhE, hmean, nullptr, nullptr);

  // graph branch (collapsed)
  edge_deg_kernel<<<dim3((NEDGE+255)/256), dim3(256), 0, stream>>>(edst, deg);
  node_dinv_kernel<<<dim3((NNODE+255)/256), dim3(256), 0, stream>>>(deg, dinv);
  edge_s1_kernel<<<dim3((NEDGE+255)/256), dim3(256), 0, stream>>>(esrc, edst, dinv, s1);
  node_c_kernel<<<dim3((NNODE+255)/256), dim3(256), 0, stream>>>(dinv, s1, cc, csum);
  edge_s2_kernel<<<dim3((NEDGE+255)/256), dim3(256), 0, stream>>>(esrc, edst, dinv, cc, s2);
  node_e_kernel<<<dim3((NNODE+255)/256), dim3(256), 0, stream>>>(dinv, s2, cc, ee);
  gvec_kernel<<<dim3(256), dim3(256), 0, stream>>>(nids, emb, ee, gvec);
  graph_final_kernel<<<dim3(1), dim3(128), 0, stream>>>(gvec, csum, W1, b1, W2, b2, mvec);

  // fusion + decoder
  fusion_kernel<<<dim3(BB), dim3(512), 0, stream>>>(hmean, mvec, Wf, bfv, WihD, bD, xgdec);
  lstm_scan_kernel<1><<<dim3(BB), dim3(512), 0, stream>>>(xgdec, WhhD, nullptr, Ahi, Alo);

  // output projection
  split_bf16_kernel<<<dim3((VV*HH/4+255)/256), dim3(256), 0, stream>>>(Wo, Bhi, Blo, VV*HH/4);
  out_gemm_kernel<<<dim3(64*(VV/64)), dim3(256), 0, stream>>>(Ahi, Alo, Bhi, Blo, bo, out);
}